// Round 1
// baseline (738.966 us; speedup 1.0000x reference)
//
#include <hip/hip_runtime.h>
#include <hip/hip_bf16.h>

// Sizes (fixed by the reference)
//  V=32000, T=48, E=128, HID=256, H=128, B=256, L=512, 4H=512
typedef unsigned short ushort_t;
typedef unsigned int uint_t;
typedef __bf16 bf16x8 __attribute__((ext_vector_type(8)));
typedef float f32x4 __attribute__((ext_vector_type(4)));
typedef float f32x16 __attribute__((ext_vector_type(16)));

#define L2E 1.44269504088896340736f
#define LN2 0.69314718055994530942f

// LDS-only barrier: does NOT drain vmcnt -> global loads/stores stay in flight.
#define WGBAR() __asm__ volatile("s_waitcnt lgkmcnt(0)\n\ts_barrier" ::: "memory")

static __device__ __forceinline__ float fexp2(float x) { return __builtin_amdgcn_exp2f(x); }
static __device__ __forceinline__ float flog2(float x) { return __builtin_amdgcn_logf(x); }
static __device__ __forceinline__ float frcp (float x) { return __builtin_amdgcn_rcpf(x); }

static __device__ __forceinline__ float sigm(float x) {
  return frcp(1.0f + fexp2(-L2E * x));
}
static __device__ __forceinline__ float tanha(float x) {
  return 1.0f - 2.0f * frcp(1.0f + fexp2(2.0f * L2E * x));
}

static __device__ __forceinline__ ushort_t f2bf(float f) {
  union { float f; uint_t u; } v; v.f = f;
  uint_t u = v.u;
  uint_t r = (u + 0x7fffu + ((u >> 16) & 1u)) >> 16;  // RNE
  return (ushort_t)r;
}
static __device__ __forceinline__ bf16x8 pack8(float4 a, float4 b) {
  uint4 u = make_uint4(
      (uint_t)f2bf(a.x) | ((uint_t)f2bf(a.y) << 16),
      (uint_t)f2bf(a.z) | ((uint_t)f2bf(a.w) << 16),
      (uint_t)f2bf(b.x) | ((uint_t)f2bf(b.y) << 16),
      (uint_t)f2bf(b.z) | ((uint_t)f2bf(b.w) << 16));
  return __builtin_bit_cast(bf16x8, u);
}
static __device__ __forceinline__ bf16x8 zero8() {
  uint4 z = make_uint4(0u, 0u, 0u, 0u);
  return __builtin_bit_cast(bf16x8, z);
}
static __device__ __forceinline__ uint2 pack4(float4 a) {
  return make_uint2((uint_t)f2bf(a.x) | ((uint_t)f2bf(a.y) << 16),
                    (uint_t)f2bf(a.z) | ((uint_t)f2bf(a.w) << 16));
}
static __device__ __forceinline__ float rdlane(float x, int l) {
  return __builtin_bit_cast(float,
      __builtin_amdgcn_readlane(__builtin_bit_cast(int, x), l));
}

// ---------------------------------------------------------------------------
// K2 v6: fully-fused BiLSTM. grid = 256 WGs x 512 thr; wg>>7 = dir,
// (wg&127)*2 = 2 batch rows. v6 attacks the LDS-issue bound:
//  - NO shuffles: 16x16x32 C-layout has both batch rows in lanes 0-15
//    (row0=reg0, row1=reg1) -> lanes 0-15 run both activation chains.
//    (-4 ds_bpermute/wave/step)
//  - xp layout [ts-pair 8][col 132][12]: per (ts,col): b0Q0..Q3, b1Q0..Q3,
//    4 u16 pad -> 6-dword col stride. Consumption = 2 aligned b64 reads
//    (bank 6*l15 mod 32: 16 distinct even banks, conflict-free).
//    Production results buffered across the 4 Q-phases (8 VGPRs) and
//    written once per 8-step block as 4 b64 (was 16 scalar u16 writes
//    with a 4-way bank conflict).
// ---------------------------------------------------------------------------
__global__ __launch_bounds__(512, 2) void k2_lstm(
    const int* __restrict__ words, const float* __restrict__ emb,
    const float* __restrict__ Wih_f, const float* __restrict__ Whh_f,
    const float* __restrict__ bih_f, const float* __restrict__ bhh_f,
    const float* __restrict__ Wih_b, const float* __restrict__ Whh_b,
    const float* __restrict__ bih_b, const float* __restrict__ bhh_b,
    ushort_t* __restrict__ h_f, ushort_t* __restrict__ h_b) {
  const int wg = blockIdx.x;
  const int dir = wg >> 7;
  const int r0 = (wg & 127) << 1;
  const float* Whh = dir ? Whh_b : Whh_f;
  const float* Wih = dir ? Wih_b : Wih_f;
  const float* bih = dir ? bih_b : bih_f;
  const float* bhh = dir ? bhh_b : bhh_f;
  ushort_t* hout = dir ? h_b : h_f;

  const int tid = threadIdx.x;
  const int w = tid >> 6;        // wave 0..7
  const int lane = tid & 63;
  const int l15 = lane & 15;
  const int kq = lane >> 4;      // 0..3

  __shared__ __align__(16) ushort_t hx[2][2][136];       //  1,088 B
  __shared__ __align__(16) ushort_t xp[2][8][132][12];   // 50,688 B
  __shared__ __align__(16) ushort_t xs[2][16][136];      //  8,704 B

  // ---- register-resident weight fragments (bf16), [quadrant][K-chunk] ----
  // B layout (16x16x32): col n = lane&15, k = (lane>>4)*8 + j
  bf16x8 wfh[4][4], wfx[4][4];
  float biasP[4];   // production bias for col w*16+l15, quadrant Q
#pragma unroll
  for (int Q = 0; Q < 4; ++Q) {
    const int n = Q * 128 + w * 16 + l15;
    biasP[Q] = bih[n] + bhh[n];
#pragma unroll
    for (int c = 0; c < 4; ++c) {
      const int k0 = c * 32 + kq * 8;
      const float* sh = Whh + n * 128 + k0;
      const float* sx = Wih + n * 128 + k0;
      wfh[Q][c] = pack8(*(const float4*)sh, *(const float4*)(sh + 4));
      wfx[Q][c] = pack8(*(const float4*)sx, *(const float4*)(sx + 4));
    }
  }

  const int uj = w * 16 + l15;
  float cst0 = 0.f, cst1 = 0.f;

  // staging thread mapping: 512 thr cover 16 rows x 128 cols (4 floats each)
  const int sm = tid >> 5;          // xs row 0..15  (tl = sm>>1, r = sm&1)
  const int sc = (tid & 31) * 4;    // col 0..124
  const int str = r0 + (sm & 1);
  const int stl = sm >> 1;

  // production pack registers (live across the 4 Q sub-phases of a block)
  uint_t pd0[4], pd1[4];
  f32x4 pc = {0.f, 0.f, 0.f, 0.f};

  // ---- prologue ----
  if (tid < 256) hx[0][tid >> 7][tid & 127] = 0;   // h(-1) = 0
  {  // stage xs[1] = x(block 0)
    const int tg = stl;
    const int tf = dir ? (511 - tg) : tg;
    const int word = words[str * 512 + tf];
    float4 av = *(const float4*)(emb + (size_t)word * 128 + sc);
    *(uint2*)&xs[1][sm][sc] = pack4(av);
  }
  WGBAR();
  // produce xp[0] from xs[1] (16 dense MFMAs/wave), bias in C-init
#pragma unroll
  for (int Q = 0; Q < 4; ++Q) {
    f32x4 pc0 = {biasP[Q], biasP[Q], biasP[Q], biasP[Q]};
#pragma unroll
    for (int c = 0; c < 4; ++c) {
      bf16x8 af = __builtin_bit_cast(bf16x8, *(const uint4*)&xs[1][l15][kq * 8 + c * 32]);
      pc0 = __builtin_amdgcn_mfma_f32_16x16x32_bf16(af, wfx[Q][c], pc0, 0, 0, 0);
    }
#pragma unroll
    for (int rr = 0; rr < 4; ++rr) {
      const uint_t bb = (uint_t)f2bf(pc0[rr]);
      if (Q == 0) pd0[rr] = bb;
      else if (Q == 1) pd0[rr] |= bb << 16;
      else if (Q == 2) pd1[rr] = bb;
      else pd1[rr] |= bb << 16;
    }
  }
#pragma unroll
  for (int rr = 0; rr < 4; ++rr)
    *(uint2*)&xp[0][kq * 2 + (rr >> 1)][uj][(rr & 1) * 4] = make_uint2(pd0[rr], pd1[rr]);
  {  // stage xs[0] = x(block 1)
    const int tg = 8 + stl;
    const int tf = dir ? (511 - tg) : tg;
    const int word = words[str * 512 + tf];
    float4 av = *(const float4*)(emb + (size_t)word * 128 + sc);
    *(uint2*)&xs[0][sm][sc] = pack4(av);
  }
  WGBAR();

  int sword = 0;
  float4 se0 = make_float4(0.f, 0.f, 0.f, 0.f);

#pragma unroll 1
  for (int i = 0; i < 64; ++i) {   // 64 blocks of 8 steps
    const int pcon = i & 1;        // consume xp[pcon]; production reads xs[pcon]
    const int ppro = pcon ^ 1;     // produce xp[ppro]; staging writes xs[ppro]
#pragma unroll
    for (int s = 0; s < 8; ++s) {
      const int t = i * 8 + s;
      const int p = t & 1;
      // xp consumption: 2 aligned b64 reads (b0: Q0..Q3, b1: Q0..Q3)
      const uint2 xq0 = *(const uint2*)&xp[pcon][s][uj][0];
      const uint2 xq1 = *(const uint2*)&xp[pcon][s][uj][4];
      // staging pipeline for x(block i+2): word @s0, emb @s2, LDS write @s6
      if (i < 62) {
        if (s == 0) {
          const int tg = (i + 2) * 8 + stl;
          const int tf = dir ? (511 - tg) : tg;
          sword = words[str * 512 + tf];
        }
        if (s == 2) se0 = *(const float4*)(emb + (size_t)sword * 128 + sc);
        if (s == 6) *(uint2*)&xs[ppro][sm][sc] = pack4(se0);
      }
      // ---- recurrence MFMAs: gates_h = h @ Whh^T (K=128) ----
      f32x4 a0 = {0.f, 0.f, 0.f, 0.f}, a1 = a0, a2 = a0, a3 = a0;
      const ushort_t* abase = &hx[p][l15 & 1][kq * 8];
#pragma unroll
      for (int c = 0; c < 4; ++c) {
        bf16x8 af = __builtin_bit_cast(bf16x8, *(const uint4*)(abase + c * 32));
        a0 = __builtin_amdgcn_mfma_f32_16x16x32_bf16(af, wfh[0][c], a0, 0, 0, 0);
        a1 = __builtin_amdgcn_mfma_f32_16x16x32_bf16(af, wfh[1][c], a1, 0, 0, 0);
        a2 = __builtin_amdgcn_mfma_f32_16x16x32_bf16(af, wfh[2][c], a2, 0, 0, 0);
        a3 = __builtin_amdgcn_mfma_f32_16x16x32_bf16(af, wfh[3][c], a3, 0, 0, 0);
      }
      // ---- production MFMAs for block i+1 (independent; fills bubbles).
      //      Results buffered in pd0/pd1; single 4x b64 LDS write at s==7.
      if (i < 63) {
        const int Q = s >> 1;
        if ((s & 1) == 0) {
          pc = f32x4{biasP[Q], biasP[Q], biasP[Q], biasP[Q]};
          bf16x8 af0 = __builtin_bit_cast(bf16x8, *(const uint4*)&xs[pcon][l15][kq * 8]);
          bf16x8 af1 = __builtin_bit_cast(bf16x8, *(const uint4*)&xs[pcon][l15][kq * 8 + 32]);
          pc = __builtin_amdgcn_mfma_f32_16x16x32_bf16(af0, wfx[Q][0], pc, 0, 0, 0);
          pc = __builtin_amdgcn_mfma_f32_16x16x32_bf16(af1, wfx[Q][1], pc, 0, 0, 0);
        } else {
          bf16x8 af2 = __builtin_bit_cast(bf16x8, *(const uint4*)&xs[pcon][l15][kq * 8 + 64]);
          bf16x8 af3 = __builtin_bit_cast(bf16x8, *(const uint4*)&xs[pcon][l15][kq * 8 + 96]);
          pc = __builtin_amdgcn_mfma_f32_16x16x32_bf16(af2, wfx[Q][2], pc, 0, 0, 0);
          pc = __builtin_amdgcn_mfma_f32_16x16x32_bf16(af3, wfx[Q][3], pc, 0, 0, 0);
#pragma unroll
          for (int rr = 0; rr < 4; ++rr) {
            const uint_t bb = (uint_t)f2bf(pc[rr]);
            if (Q == 0) pd0[rr] = bb;
            else if (Q == 1) pd0[rr] |= bb << 16;
            else if (Q == 2) pd1[rr] = bb;
            else pd1[rr] |= bb << 16;
          }
          if (s == 7) {
#pragma unroll
            for (int rr = 0; rr < 4; ++rr)
              *(uint2*)&xp[ppro][kq * 2 + (rr >> 1)][uj][(rr & 1) * 4] =
                  make_uint2(pd0[rr], pd1[rr]);
          }
        }
      }
      // ---- gates: both batch rows live in regs [0]/[1] (C rows 0/1) ----
      const float x00 = __builtin_bit_cast(float, xq0.x << 16);
      const float x01 = __builtin_bit_cast(float, xq0.x & 0xffff0000u);
      const float x02 = __builtin_bit_cast(float, xq0.y << 16);
      const float x03 = __builtin_bit_cast(float, xq0.y & 0xffff0000u);
      const float x10 = __builtin_bit_cast(float, xq1.x << 16);
      const float x11 = __builtin_bit_cast(float, xq1.x & 0xffff0000u);
      const float x12 = __builtin_bit_cast(float, xq1.y << 16);
      const float x13 = __builtin_bit_cast(float, xq1.y & 0xffff0000u);
      const float g00 = a0[0] + x00, g01 = a1[0] + x01;
      const float g02 = a2[0] + x02, g03 = a3[0] + x03;
      const float g10 = a0[1] + x10, g11 = a1[1] + x11;
      const float g12 = a2[1] + x12, g13 = a3[1] + x13;
      // activations, two independent chains (ILP); lanes>=16 compute
      // identical duplicates (A rows 4,5,... replicate rows 0,1), stores guarded
      const float si0 = sigm(g00), sf0 = sigm(g01), so0 = sigm(g03);
      const float tg0 = tanha(g02);
      const float si1 = sigm(g10), sf1 = sigm(g11), so1 = sigm(g13);
      const float tg1 = tanha(g12);
      cst0 = sf0 * cst0 + si0 * tg0;
      cst1 = sf1 * cst1 + si1 * tg1;
      const float h0 = so0 * tanha(cst0);
      const float h1 = so1 * tanha(cst1);
      const ushort_t hb0 = f2bf(h0);
      const ushort_t hb1 = f2bf(h1);
      if (lane < 16) {
        hx[p ^ 1][0][uj] = hb0;
        hx[p ^ 1][1][uj] = hb1;
        const int tf = dir ? (511 - t) : t;
        ushort_t* hb = hout + (size_t)(tf * 256 + r0) * 128 + uj;
        hb[0]   = hb0;   // stays in flight across WGBAR
        hb[128] = hb1;
      }
      WGBAR();
    }
  }
}

// ---------------------------------------------------------------------------
// K3: emis[t*256+b][48] = [h_f|h_b] @ Wout^T + bout  (fp32 out)
// ---------------------------------------------------------------------------
__global__ __launch_bounds__(256, 2) void k3_emis(
    const ushort_t* __restrict__ h_f, const ushort_t* __restrict__ h_b,
    const float* __restrict__ Wout, const float* __restrict__ bout,
    float* __restrict__ emis) {
  const int w = threadIdx.x >> 6;
  const int lane = threadIdx.x & 63;
  const int m31 = lane & 31;
  const int q = lane >> 5;
  const int Mbase = blockIdx.x * 128 + w * 32;

  bf16x8 bfr[2][16];
  float bo[2];
#pragma unroll
  for (int T = 0; T < 2; ++T) {
    const int n = T * 32 + m31;
    if (n < 48) {
      bo[T] = bout[n];
#pragma unroll
      for (int c = 0; c < 16; ++c) {
        const float* src = Wout + n * 256 + c * 16 + q * 8;
        bfr[T][c] = pack8(*(const float4*)src, *(const float4*)(src + 4));
      }
    } else {
      bo[T] = 0.f;
#pragma unroll
      for (int c = 0; c < 16; ++c) bfr[T][c] = zero8();
    }
  }
  f32x16 acc0{}, acc1{};
  const ushort_t* hrf = h_f + (long)(Mbase + m31) * 128;
  const ushort_t* hrb = h_b + (long)(Mbase + m31) * 128;
#pragma unroll
  for (int c = 0; c < 16; ++c) {
    const ushort_t* src = (c < 8) ? (hrf + c * 16 + q * 8) : (hrb + (c - 8) * 16 + q * 8);
    bf16x8 af = __builtin_bit_cast(bf16x8, *(const uint4*)src);
    acc0 = __builtin_amdgcn_mfma_f32_32x32x16_bf16(af, bfr[0][c], acc0, 0, 0, 0);
    acc1 = __builtin_amdgcn_mfma_f32_32x32x16_bf16(af, bfr[1][c], acc1, 0, 0, 0);
  }
#pragma unroll
  for (int T = 0; T < 2; ++T) {
    const int n = T * 32 + m31;
    if (n >= 48) continue;
    f32x16 A = T ? acc1 : acc0;
#pragma unroll
    for (int r = 0; r < 16; ++r) {
      const int row = (r & 3) + ((r >> 2) << 3) + (q << 2);
      emis[(long)(Mbase + row) * 48 + n] = A[r] + bo[T];
    }
  }
}

// ---------------------------------------------------------------------------
// K4 v5: fused CRF forward (wave 0) + gold-path numerator (wave 1).
// Denominator matvec d <- (d @ P) * E now uses v_readlane broadcast:
// no LDS round-trip (was: ds_write + lgkmcnt(0) + 12x ds_read_b128 on a
// single-wave serial chain). 256 WGs x 128 thr.
// ---------------------------------------------------------------------------
__global__ void k4_den_num(const int* __restrict__ words, const int* __restrict__ tags,
                           const float* __restrict__ emis, const float* __restrict__ trans,
                           const float* __restrict__ st, const float* __restrict__ et,
                           float* __restrict__ denom, float* __restrict__ num) {
  const int b = blockIdx.x;
  const int tid = threadIdx.x;
  const int j = tid & 63;

  if (tid >= 64) {   // ---- wave 1: numerator (gold path score) ----
    float s = 0.f;
    int cnt = 0;
#pragma unroll 1
    for (int s8 = 0; s8 < 8; ++s8) {
      const int t = j + (s8 << 6);
      const int wv = words[b * 512 + t];
      const int tg = tags[b * 512 + t];
      const bool mt = (wv != 0);
      cnt += mt ? 1 : 0;
      if (t == 0) {
        s += st[tg] + emis[b * 48 + tg];
      } else if (mt) {
        const int tp = tags[b * 512 + t - 1];
        s += trans[tp * 48 + tg] + emis[(t * 256 + b) * 48 + tg];
      }
    }
#pragma unroll
    for (int d = 32; d; d >>= 1) {
      s += __shfl_xor(s, d, 64);
      cnt += __shfl_xor(cnt, d, 64);
    }
    if (j == 0) {
      const int lt = tags[b * 512 + cnt - 1];
      num[b] = s + et[lt];
    }
    return;
  }

  // ---- wave 0: denominator, forward algorithm in linear domain ----
  const bool v = j < 48;
  const int jj = v ? j : 47;
  float pcol[48];
#pragma unroll
  for (int i = 0; i < 48; ++i) pcol[i] = fexp2(trans[i * 48 + jj] * L2E);

  // mask bits: mb[q] bit s = (words[b*512 + q*64 + s] != 0)
  unsigned long long mb[8];
#pragma unroll
  for (int q = 0; q < 8; ++q)
    mb[q] = __ballot(words[b * 512 + q * 64 + j] != 0);

  float d = v ? fexp2((st[j] + emis[b * 48 + j]) * L2E) : 0.f;
  int S = 0, e_pend = 0;

  float em0 = v ? emis[(1 * 256 + b) * 48 + j] : 0.f;
  float em1 = v ? emis[(2 * 256 + b) * 48 + j] : 0.f;
  float em2 = v ? emis[(3 * 256 + b) * 48 + j] : 0.f;
  float Ecur = fexp2(em0 * L2E);

#pragma unroll 1
  for (int q = 0; q < 8; ++q) {
    const unsigned long long m = mb[q];
    const int s0 = (q == 0) ? 1 : 0;
#pragma unroll 1
    for (int s = s0; s < 64; ++s) {
      const int t = q * 64 + s;
      float E = Ecur;
      int eApp = 0;
      if ((s & 7) == 2) {   // fold lagged renorm into E (uniform branch)
        const float sc = __builtin_bit_cast(float, (uint_t)(127 - e_pend) << 23);
        E *= sc;
        eApp = e_pend;
      }
      const int tn = min(511, t + 3);
      em0 = em1; em1 = em2;
      em2 = v ? emis[(tn * 256 + b) * 48 + j] : 0.f;   // vmcnt path, depth-3
      const float En = fexp2(em0 * L2E);               // E for t+1, off-chain

      // matvec: nxt_j = sum_i d_i * P[i][j]  via scalar-file broadcast
      float sA = 0.f, sB = 0.f, sC = 0.f, sD = 0.f;
#pragma unroll
      for (int i4 = 0; i4 < 12; ++i4) {
        sA = fmaf(rdlane(d, 4 * i4 + 0), pcol[4 * i4 + 0], sA);
        sB = fmaf(rdlane(d, 4 * i4 + 1), pcol[4 * i4 + 1], sB);
        sC = fmaf(rdlane(d, 4 * i4 + 2), pcol[4 * i4 + 2], sC);
        sD = fmaf(rdlane(d, 4 * i4 + 3), pcol[4 * i4 + 3], sD);
      }
      const float nxt = ((sA + sB) + (sC + sD)) * E;
      if ((m >> s) & 1ull) {   // wave-uniform scalar branch, no memory
        d = v ? nxt : 0.f;
        S += eApp;
      }
      if ((s & 7) == 0) {      // lagged exponent measurement (any lane works)
        const int db = __builtin_amdgcn_readfirstlane(__builtin_bit_cast(int, d));
        e_pend = ((db >> 23) & 0xff) - 127;
      }
      Ecur = En;
    }
  }
  float uf = v ? d * fexp2(et[j] * L2E) : 0.f;
#pragma unroll
  for (int dd = 32; dd; dd >>= 1) uf += __shfl_xor(uf, dd, 64);
  if (j == 0) denom[b] = ((float)S + flog2(uf)) * LN2;
}

// ---------------------------------------------------------------------------
// K5: loss = -mean(num - denom)
// ---------------------------------------------------------------------------
__global__ void k5_loss(const float* __restrict__ num, const float* __restrict__ denom,
                        float* __restrict__ out) {
  const int tid = threadIdx.x;
  float v = num[tid] - denom[tid];
#pragma unroll
  for (int d = 32; d; d >>= 1) v += __shfl_xor(v, d, 64);
  __shared__ float p[4];
  if ((tid & 63) == 0) p[tid >> 6] = v;
  __syncthreads();
  if (tid == 0) out[0] = -(p[0] + p[1] + p[2] + p[3]) * (1.0f / 256.0f);
}

// ---------------------------------------------------------------------------
extern "C" void kernel_launch(void* const* d_in, const int* in_sizes, int n_in,
                              void* d_out, int out_size, void* d_ws, size_t ws_size,
                              hipStream_t stream) {
  (void)in_sizes; (void)n_in; (void)out_size; (void)ws_size;
  const int*   words = (const int*)d_in[0];
  const int*   tags  = (const int*)d_in[1];
  // d_in[2] = mask (bool) -- unused; reconstructed as words != 0
  const float* emb   = (const float*)d_in[3];
  const float* Wih_f = (const float*)d_in[4];
  const float* Whh_f = (const float*)d_in[5];
  const float* bih_f = (const float*)d_in[6];
  const float* bhh_f = (const float*)d_in[7];
  const float* Wih_b = (const float*)d_in[8];
  const float* Whh_b = (const float*)d_in[9];
  const float* bih_b = (const float*)d_in[10];
  const float* bhh_b = (const float*)d_in[11];
  const float* Wout  = (const float*)d_in[12];
  const float* bout  = (const float*)d_in[13];
  const float* trans = (const float*)d_in[14];
  const float* st    = (const float*)d_in[15];
  const float* et    = (const float*)d_in[16];

  char* ws = (char*)d_ws;
  ushort_t* h_f   = (ushort_t*)(ws);                    // 33,554,432 B
  ushort_t* h_b   = (ushort_t*)(ws + 33554432);         // 33,554,432 B
  float*    emis  = (float*)   (ws + 67108864);         // 25,165,824 B
  float*    denom = (float*)   (ws + 92274688);         //      1,024 B
  float*    num   = (float*)   (ws + 92275712);         //      1,024 B
  // total ws needed: ~92.3 MB (within the known-good 125.8 MB envelope)

  k2_lstm    <<<256, 512, 0, stream>>>(words, emb,
                                       Wih_f, Whh_f, bih_f, bhh_f,
                                       Wih_b, Whh_b, bih_b, bhh_b,
                                       h_f, h_b);
  k3_emis    <<<1024, 256, 0, stream>>>(h_f, h_b, Wout, bout, emis);
  k4_den_num <<<256, 128, 0, stream>>>(words, tags, emis, trans, st, et, denom, num);
  k5_loss    <<<1, 256, 0, stream>>>(num, denom, (float*)d_out);
}

// Round 2
// 624.918 us; speedup vs baseline: 1.1825x; 1.1825x over previous
//
#include <hip/hip_runtime.h>
#include <hip/hip_bf16.h>

// Sizes (fixed by the reference)
//  V=32000, T=48, E=128, HID=256, H=128, B=256, L=512, 4H=512
typedef unsigned short ushort_t;
typedef unsigned int uint_t;
typedef __bf16 bf16x8 __attribute__((ext_vector_type(8)));
typedef float f32x4 __attribute__((ext_vector_type(4)));
typedef float f32x16 __attribute__((ext_vector_type(16)));

#define L2E 1.44269504088896340736f
#define LN2 0.69314718055994530942f

// LDS-only barrier: does NOT drain vmcnt -> global loads/stores stay in flight.
#define WGBAR() __asm__ volatile("s_waitcnt lgkmcnt(0)\n\ts_barrier" ::: "memory")
// In-wave LDS RAW fence for single-wave workgroups.
#define LGKM0() __asm__ volatile("s_waitcnt lgkmcnt(0)" ::: "memory")

static __device__ __forceinline__ float fexp2(float x) { return __builtin_amdgcn_exp2f(x); }
static __device__ __forceinline__ float flog2(float x) { return __builtin_amdgcn_logf(x); }
static __device__ __forceinline__ float frcp (float x) { return __builtin_amdgcn_rcpf(x); }

static __device__ __forceinline__ float sigm(float x) {
  return frcp(1.0f + fexp2(-L2E * x));
}
static __device__ __forceinline__ float tanha(float x) {
  return 1.0f - 2.0f * frcp(1.0f + fexp2(2.0f * L2E * x));
}

static __device__ __forceinline__ ushort_t f2bf(float f) {
  union { float f; uint_t u; } v; v.f = f;
  uint_t u = v.u;
  uint_t r = (u + 0x7fffu + ((u >> 16) & 1u)) >> 16;  // RNE
  return (ushort_t)r;
}
static __device__ __forceinline__ bf16x8 pack8(float4 a, float4 b) {
  uint4 u = make_uint4(
      (uint_t)f2bf(a.x) | ((uint_t)f2bf(a.y) << 16),
      (uint_t)f2bf(a.z) | ((uint_t)f2bf(a.w) << 16),
      (uint_t)f2bf(b.x) | ((uint_t)f2bf(b.y) << 16),
      (uint_t)f2bf(b.z) | ((uint_t)f2bf(b.w) << 16));
  return __builtin_bit_cast(bf16x8, u);
}
static __device__ __forceinline__ bf16x8 zero8() {
  uint4 z = make_uint4(0u, 0u, 0u, 0u);
  return __builtin_bit_cast(bf16x8, z);
}
static __device__ __forceinline__ uint2 pack4(float4 a) {
  return make_uint2((uint_t)f2bf(a.x) | ((uint_t)f2bf(a.y) << 16),
                    (uint_t)f2bf(a.z) | ((uint_t)f2bf(a.w) << 16));
}

// ---------------------------------------------------------------------------
// K2 v7: fully-fused BiLSTM. grid = 256 WGs x 512 thr; wg>>7 = dir,
// (wg&127)*2 = 2 batch rows. v7 = v5 structure with two strictly-free deltas:
//  - gate redistribution WITHOUT shuffles AND without duplicated activations:
//    in the 16x16x32 C layout, A rows alternate batch0/batch1, so EVERY lane
//    holds batch0 gates in reg[0] and batch1 gates in reg[1]. Lane's own
//    (row,col) pair is (ur = (lane>>4)&1, uj): g = ur ? a[1] : a[0] -- one
//    v_cndmask per gate, zero DS ops, one activation chain per lane (v5 cost).
//  - xp production: buffer Q0..Q3 across the 4 phases in regs (pd0/pd1),
//    single 4x ds_write_b64 at s==7 (v5's 16 scalar u16 scatter writes had a
//    4-way bank conflict).
// Raw lgkm-only barriers keep global loads/stores in flight across steps.
// ---------------------------------------------------------------------------
__global__ __launch_bounds__(512, 2) void k2_lstm(
    const int* __restrict__ words, const float* __restrict__ emb,
    const float* __restrict__ Wih_f, const float* __restrict__ Whh_f,
    const float* __restrict__ bih_f, const float* __restrict__ bhh_f,
    const float* __restrict__ Wih_b, const float* __restrict__ Whh_b,
    const float* __restrict__ bih_b, const float* __restrict__ bhh_b,
    ushort_t* __restrict__ h_f, ushort_t* __restrict__ h_b) {
  const int wg = blockIdx.x;
  const int dir = wg >> 7;
  const int r0 = (wg & 127) << 1;
  const float* Whh = dir ? Whh_b : Whh_f;
  const float* Wih = dir ? Wih_b : Wih_f;
  const float* bih = dir ? bih_b : bih_f;
  const float* bhh = dir ? bhh_b : bhh_f;
  ushort_t* hout = dir ? h_b : h_f;

  const int tid = threadIdx.x;
  const int w = tid >> 6;        // wave 0..7
  const int lane = tid & 63;
  const int l15 = lane & 15;
  const int kq = lane >> 4;      // 0..3

  __shared__ __align__(16) ushort_t hx[2][2][136];      //  1,088 B
  __shared__ __align__(16) ushort_t xp[2][16][128][4];  // 32,768 B
  __shared__ __align__(16) ushort_t xs[2][16][136];     //  8,704 B

  // ---- register-resident weight fragments (bf16), [quadrant][K-chunk] ----
  // B layout (16x16x32): col n = lane&15, k = (lane>>4)*8 + j
  bf16x8 wfh[4][4], wfx[4][4];
  float biasP[4];   // production bias for col w*16+l15, quadrant Q
#pragma unroll
  for (int Q = 0; Q < 4; ++Q) {
    const int n = Q * 128 + w * 16 + l15;
    biasP[Q] = bih[n] + bhh[n];
#pragma unroll
    for (int c = 0; c < 4; ++c) {
      const int k0 = c * 32 + kq * 8;
      const float* sh = Whh + n * 128 + k0;
      const float* sx = Wih + n * 128 + k0;
      wfh[Q][c] = pack8(*(const float4*)sh, *(const float4*)(sh + 4));
      wfx[Q][c] = pack8(*(const float4*)sx, *(const float4*)(sx + 4));
    }
  }

  const int ur = (lane >> 4) & 1;
  const int uj = w * 16 + l15;
  float cst = 0.f;

  // staging thread mapping: 512 thr cover 16 rows x 128 cols (4 floats each)
  const int sm = tid >> 5;          // xs row 0..15  (tl = sm>>1, r = sm&1)
  const int sc = (tid & 31) * 4;    // col 0..124
  const int str = r0 + (sm & 1);
  const int stl = sm >> 1;

  // production pack registers (live across the 4 Q sub-phases of a block)
  uint_t pd0[4], pd1[4];
  f32x4 pc = {0.f, 0.f, 0.f, 0.f};

  // ---- prologue ----
  if (tid < 256) hx[0][tid >> 7][tid & 127] = 0;   // h(-1) = 0
  {  // stage xs[1] = x(block 0)
    const int tg = stl;
    const int tf = dir ? (511 - tg) : tg;
    const int word = words[str * 512 + tf];
    float4 av = *(const float4*)(emb + (size_t)word * 128 + sc);
    *(uint2*)&xs[1][sm][sc] = pack4(av);
  }
  WGBAR();
  // produce xp[0] from xs[1] (16 dense MFMAs/wave), bias in C-init
#pragma unroll
  for (int Q = 0; Q < 4; ++Q) {
    f32x4 pc0 = {biasP[Q], biasP[Q], biasP[Q], biasP[Q]};
#pragma unroll
    for (int c = 0; c < 4; ++c) {
      bf16x8 af = __builtin_bit_cast(bf16x8, *(const uint4*)&xs[1][l15][kq * 8 + c * 32]);
      pc0 = __builtin_amdgcn_mfma_f32_16x16x32_bf16(af, wfx[Q][c], pc0, 0, 0, 0);
    }
#pragma unroll
    for (int rr = 0; rr < 4; ++rr) {
      const uint_t bb = (uint_t)f2bf(pc0[rr]);
      if (Q == 0) pd0[rr] = bb;
      else if (Q == 1) pd0[rr] |= bb << 16;
      else if (Q == 2) pd1[rr] = bb;
      else pd1[rr] |= bb << 16;
    }
  }
#pragma unroll
  for (int rr = 0; rr < 4; ++rr)
    *(uint2*)&xp[0][kq * 4 + rr][uj][0] = make_uint2(pd0[rr], pd1[rr]);
  {  // stage xs[0] = x(block 1)
    const int tg = 8 + stl;
    const int tf = dir ? (511 - tg) : tg;
    const int word = words[str * 512 + tf];
    float4 av = *(const float4*)(emb + (size_t)word * 128 + sc);
    *(uint2*)&xs[0][sm][sc] = pack4(av);
  }
  WGBAR();

  int sword = 0;
  float4 se0 = make_float4(0.f, 0.f, 0.f, 0.f);

#pragma unroll 1
  for (int i = 0; i < 64; ++i) {   // 64 blocks of 8 steps
    const int pcon = i & 1;        // consume xp[pcon]; production reads xs[pcon]
    const int ppro = pcon ^ 1;     // produce xp[ppro]; staging writes xs[ppro]
#pragma unroll
    for (int s = 0; s < 8; ++s) {
      const int t = i * 8 + s;
      const int p = t & 1;
      // xp consumption: one b64 read (Q0..Q3 packed for this lane's (ur,uj))
      const uint2 xq = *(const uint2*)&xp[pcon][2 * s + ur][uj][0];
      // staging pipeline for x(block i+2): word @s0, emb @s2, LDS write @s6
      if (i < 62) {
        if (s == 0) {
          const int tg = (i + 2) * 8 + stl;
          const int tf = dir ? (511 - tg) : tg;
          sword = words[str * 512 + tf];
        }
        if (s == 2) se0 = *(const float4*)(emb + (size_t)sword * 128 + sc);
        if (s == 6) *(uint2*)&xs[ppro][sm][sc] = pack4(se0);
      }
      // ---- recurrence MFMAs: gates_h = h @ Whh^T (K=128) ----
      f32x4 a0 = {0.f, 0.f, 0.f, 0.f}, a1 = a0, a2 = a0, a3 = a0;
      const ushort_t* abase = &hx[p][l15 & 1][kq * 8];
#pragma unroll
      for (int c = 0; c < 4; ++c) {
        bf16x8 af = __builtin_bit_cast(bf16x8, *(const uint4*)(abase + c * 32));
        a0 = __builtin_amdgcn_mfma_f32_16x16x32_bf16(af, wfh[0][c], a0, 0, 0, 0);
        a1 = __builtin_amdgcn_mfma_f32_16x16x32_bf16(af, wfh[1][c], a1, 0, 0, 0);
        a2 = __builtin_amdgcn_mfma_f32_16x16x32_bf16(af, wfh[2][c], a2, 0, 0, 0);
        a3 = __builtin_amdgcn_mfma_f32_16x16x32_bf16(af, wfh[3][c], a3, 0, 0, 0);
      }
      // ---- production MFMAs for block i+1 (independent; fills bubbles).
      //      Results buffered in pd0/pd1; single 4x b64 LDS write at s==7.
      if (i < 63) {
        const int Q = s >> 1;
        if ((s & 1) == 0) {
          pc = f32x4{biasP[Q], biasP[Q], biasP[Q], biasP[Q]};
          bf16x8 af0 = __builtin_bit_cast(bf16x8, *(const uint4*)&xs[pcon][l15][kq * 8]);
          bf16x8 af1 = __builtin_bit_cast(bf16x8, *(const uint4*)&xs[pcon][l15][kq * 8 + 32]);
          pc = __builtin_amdgcn_mfma_f32_16x16x32_bf16(af0, wfx[Q][0], pc, 0, 0, 0);
          pc = __builtin_amdgcn_mfma_f32_16x16x32_bf16(af1, wfx[Q][1], pc, 0, 0, 0);
        } else {
          bf16x8 af2 = __builtin_bit_cast(bf16x8, *(const uint4*)&xs[pcon][l15][kq * 8 + 64]);
          bf16x8 af3 = __builtin_bit_cast(bf16x8, *(const uint4*)&xs[pcon][l15][kq * 8 + 96]);
          pc = __builtin_amdgcn_mfma_f32_16x16x32_bf16(af2, wfx[Q][2], pc, 0, 0, 0);
          pc = __builtin_amdgcn_mfma_f32_16x16x32_bf16(af3, wfx[Q][3], pc, 0, 0, 0);
#pragma unroll
          for (int rr = 0; rr < 4; ++rr) {
            const uint_t bb = (uint_t)f2bf(pc[rr]);
            if (Q == 0) pd0[rr] = bb;
            else if (Q == 1) pd0[rr] |= bb << 16;
            else if (Q == 2) pd1[rr] = bb;
            else pd1[rr] |= bb << 16;
          }
          if (s == 7) {
#pragma unroll
            for (int rr = 0; rr < 4; ++rr)
              *(uint2*)&xp[ppro][kq * 4 + rr][uj][0] = make_uint2(pd0[rr], pd1[rr]);
          }
        }
      }
      // ---- gates: lane's own (ur,uj) pair -- reg[0]=batch0, reg[1]=batch1
      //      (A rows alternate b0/b1, so C rows 0,4,8,12=b0 and 1,5,9,13=b1;
      //       every lane group holds BOTH batches in regs 0/1). No shuffles.
      const float g0 = (ur ? a0[1] : a0[0]) + __builtin_bit_cast(float, xq.x << 16);
      const float g1 = (ur ? a1[1] : a1[0]) + __builtin_bit_cast(float, xq.x & 0xffff0000u);
      const float g2 = (ur ? a2[1] : a2[0]) + __builtin_bit_cast(float, xq.y << 16);
      const float g3 = (ur ? a3[1] : a3[0]) + __builtin_bit_cast(float, xq.y & 0xffff0000u);
      // activations (one chain per lane; lanes>=32 duplicate, stores guarded)
      const float si = sigm(g0), sf = sigm(g1), so = sigm(g3);
      const float tg = tanha(g2);
      cst = sf * cst + si * tg;
      const float h = so * tanha(cst);
      const ushort_t hb = f2bf(h);
      if (lane < 32) {
        hx[p ^ 1][ur][uj] = hb;
        const int tf = dir ? (511 - t) : t;
        hout[(tf * 256 + r0 + ur) * 128 + uj] = hb;  // stays in flight
      }
      WGBAR();
    }
  }
}

// ---------------------------------------------------------------------------
// K3: emis[t*256+b][48] = [h_f|h_b] @ Wout^T + bout  (fp32 out)
// ---------------------------------------------------------------------------
__global__ __launch_bounds__(256, 2) void k3_emis(
    const ushort_t* __restrict__ h_f, const ushort_t* __restrict__ h_b,
    const float* __restrict__ Wout, const float* __restrict__ bout,
    float* __restrict__ emis) {
  const int w = threadIdx.x >> 6;
  const int lane = threadIdx.x & 63;
  const int m31 = lane & 31;
  const int q = lane >> 5;
  const int Mbase = blockIdx.x * 128 + w * 32;

  bf16x8 bfr[2][16];
  float bo[2];
#pragma unroll
  for (int T = 0; T < 2; ++T) {
    const int n = T * 32 + m31;
    if (n < 48) {
      bo[T] = bout[n];
#pragma unroll
      for (int c = 0; c < 16; ++c) {
        const float* src = Wout + n * 256 + c * 16 + q * 8;
        bfr[T][c] = pack8(*(const float4*)src, *(const float4*)(src + 4));
      }
    } else {
      bo[T] = 0.f;
#pragma unroll
      for (int c = 0; c < 16; ++c) bfr[T][c] = zero8();
    }
  }
  f32x16 acc0{}, acc1{};
  const ushort_t* hrf = h_f + (long)(Mbase + m31) * 128;
  const ushort_t* hrb = h_b + (long)(Mbase + m31) * 128;
#pragma unroll
  for (int c = 0; c < 16; ++c) {
    const ushort_t* src = (c < 8) ? (hrf + c * 16 + q * 8) : (hrb + (c - 8) * 16 + q * 8);
    bf16x8 af = __builtin_bit_cast(bf16x8, *(const uint4*)src);
    acc0 = __builtin_amdgcn_mfma_f32_32x32x16_bf16(af, bfr[0][c], acc0, 0, 0, 0);
    acc1 = __builtin_amdgcn_mfma_f32_32x32x16_bf16(af, bfr[1][c], acc1, 0, 0, 0);
  }
#pragma unroll
  for (int T = 0; T < 2; ++T) {
    const int n = T * 32 + m31;
    if (n >= 48) continue;
    f32x16 A = T ? acc1 : acc0;
#pragma unroll
    for (int r = 0; r < 16; ++r) {
      const int row = (r & 3) + ((r >> 2) << 3) + (q << 2);
      emis[(long)(Mbase + row) * 48 + n] = A[r] + bo[T];
    }
  }
}

// ---------------------------------------------------------------------------
// K4 v4 (round-0 measured-good): CRF forward, linear domain.  d <- (d @ P) * E.
//  - words mask precomputed as 8 ballot u64s (SGPR): zero in-loop memory for
//    the mask. Renorm every 8 steps via readfirstlane exponent, folded 2
//    steps later. 256 WGs x 64 thr (single wave).
// ---------------------------------------------------------------------------
__global__ void k4_den(const int* __restrict__ words, const float* __restrict__ emis,
                       const float* __restrict__ trans, const float* __restrict__ st,
                       const float* __restrict__ et, float* __restrict__ denom) {
  const int b = blockIdx.x;
  const int j = threadIdx.x;
  const bool v = j < 48;
  const int jj = v ? j : 47;
  float pcol[48];
#pragma unroll
  for (int i = 0; i < 48; ++i) pcol[i] = fexp2(trans[i * 48 + jj] * L2E);

  // mask bits: mb[q] bit s = (words[b*512 + q*64 + s] != 0)
  unsigned long long mb[8];
#pragma unroll
  for (int q = 0; q < 8; ++q)
    mb[q] = __ballot(words[b * 512 + q * 64 + j] != 0);

  __shared__ __align__(16) float ul[64];
  float d = v ? fexp2((st[j] + emis[b * 48 + j]) * L2E) : 0.f;
  int S = 0, e_pend = 0;

  float em0 = v ? emis[(1 * 256 + b) * 48 + j] : 0.f;
  float em1 = v ? emis[(2 * 256 + b) * 48 + j] : 0.f;
  float em2 = v ? emis[(3 * 256 + b) * 48 + j] : 0.f;
  float Ecur = fexp2(em0 * L2E);

#pragma unroll 1
  for (int q = 0; q < 8; ++q) {
    const unsigned long long m = mb[q];
    const int s0 = (q == 0) ? 1 : 0;
#pragma unroll 1
    for (int s = s0; s < 64; ++s) {
      const int t = q * 64 + s;
      float E = Ecur;
      int eApp = 0;
      if ((s & 7) == 2) {   // fold lagged renorm into E (uniform branch)
        const float sc = __builtin_bit_cast(float, (uint_t)(127 - e_pend) << 23);
        E *= sc;
        eApp = e_pend;
      }
      const int tn = min(511, t + 3);
      em0 = em1; em1 = em2;
      em2 = v ? emis[(tn * 256 + b) * 48 + j] : 0.f;   // vmcnt path, depth-3
      const float En = fexp2(em0 * L2E);               // E for t+1, off-chain

      ul[j] = d;
      LGKM0();
      float sA = 0.f, sB = 0.f, sC = 0.f, sD = 0.f;
#pragma unroll
      for (int i4 = 0; i4 < 12; ++i4) {
        float4 uu = *(const float4*)&ul[i4 * 4];
        sA = fmaf(uu.x, pcol[i4 * 4 + 0], sA);
        sB = fmaf(uu.y, pcol[i4 * 4 + 1], sB);
        sC = fmaf(uu.z, pcol[i4 * 4 + 2], sC);
        sD = fmaf(uu.w, pcol[i4 * 4 + 3], sD);
      }
      const float nxt = ((sA + sB) + (sC + sD)) * E;
      if ((m >> s) & 1ull) {   // wave-uniform scalar branch, no memory
        d = v ? nxt : 0.f;
        S += eApp;
      }
      if ((s & 7) == 0) {      // lagged exponent measurement (any lane works)
        const int db = __builtin_amdgcn_readfirstlane(__builtin_bit_cast(int, d));
        e_pend = ((db >> 23) & 0xff) - 127;
      }
      Ecur = En;
    }
  }
  float uf = v ? d * fexp2(et[j] * L2E) : 0.f;
#pragma unroll
  for (int dd = 32; dd; dd >>= 1) uf += __shfl_xor(uf, dd, 64);
  if (j == 0) denom[b] = ((float)S + flog2(uf)) * LN2;
}

// ---------------------------------------------------------------------------
// K4b: CRF numerator (gold path score).
// ---------------------------------------------------------------------------
__global__ void k4b_num(const int* __restrict__ words, const int* __restrict__ tags,
                        const float* __restrict__ emis, const float* __restrict__ trans,
                        const float* __restrict__ st, const float* __restrict__ et,
                        float* __restrict__ num) {
  const int b = blockIdx.x;
  const int lane = threadIdx.x;
  float s = 0.f;
  int cnt = 0;
#pragma unroll 1
  for (int s8 = 0; s8 < 8; ++s8) {
    const int t = lane + (s8 << 6);
    const int wv = words[b * 512 + t];
    const int tg = tags[b * 512 + t];
    const bool mt = (wv != 0);
    cnt += mt ? 1 : 0;
    if (t == 0) {
      s += st[tg] + emis[b * 48 + tg];
    } else if (mt) {
      const int tp = tags[b * 512 + t - 1];
      s += trans[tp * 48 + tg] + emis[(t * 256 + b) * 48 + tg];
    }
  }
#pragma unroll
  for (int d = 32; d; d >>= 1) {
    s += __shfl_xor(s, d, 64);
    cnt += __shfl_xor(cnt, d, 64);
  }
  if (lane == 0) {
    const int lt = tags[b * 512 + cnt - 1];
    num[b] = s + et[lt];
  }
}

// ---------------------------------------------------------------------------
// K5: loss = -mean(num - denom)
// ---------------------------------------------------------------------------
__global__ void k5_loss(const float* __restrict__ num, const float* __restrict__ denom,
                        float* __restrict__ out) {
  const int tid = threadIdx.x;
  float v = num[tid] - denom[tid];
#pragma unroll
  for (int d = 32; d; d >>= 1) v += __shfl_xor(v, d, 64);
  __shared__ float p[4];
  if ((tid & 63) == 0) p[tid >> 6] = v;
  __syncthreads();
  if (tid == 0) out[0] = -(p[0] + p[1] + p[2] + p[3]) * (1.0f / 256.0f);
}

// ---------------------------------------------------------------------------
extern "C" void kernel_launch(void* const* d_in, const int* in_sizes, int n_in,
                              void* d_out, int out_size, void* d_ws, size_t ws_size,
                              hipStream_t stream) {
  (void)in_sizes; (void)n_in; (void)out_size; (void)ws_size;
  const int*   words = (const int*)d_in[0];
  const int*   tags  = (const int*)d_in[1];
  // d_in[2] = mask (bool) -- unused; reconstructed as words != 0
  const float* emb   = (const float*)d_in[3];
  const float* Wih_f = (const float*)d_in[4];
  const float* Whh_f = (const float*)d_in[5];
  const float* bih_f = (const float*)d_in[6];
  const float* bhh_f = (const float*)d_in[7];
  const float* Wih_b = (const float*)d_in[8];
  const float* Whh_b = (const float*)d_in[9];
  const float* bih_b = (const float*)d_in[10];
  const float* bhh_b = (const float*)d_in[11];
  const float* Wout  = (const float*)d_in[12];
  const float* bout  = (const float*)d_in[13];
  const float* trans = (const float*)d_in[14];
  const float* st    = (const float*)d_in[15];
  const float* et    = (const float*)d_in[16];

  char* ws = (char*)d_ws;
  ushort_t* h_f   = (ushort_t*)(ws);                    // 33,554,432 B
  ushort_t* h_b   = (ushort_t*)(ws + 33554432);         // 33,554,432 B
  float*    emis  = (float*)   (ws + 67108864);         // 25,165,824 B
  float*    denom = (float*)   (ws + 92274688);         //      1,024 B
  float*    num   = (float*)   (ws + 92275712);         //      1,024 B
  // total ws needed: ~92.3 MB (within the known-good 125.8 MB envelope)

  k2_lstm <<<256, 512, 0, stream>>>(words, emb,
                                    Wih_f, Whh_f, bih_f, bhh_f,
                                    Wih_b, Whh_b, bih_b, bhh_b,
                                    h_f, h_b);
  k3_emis <<<1024, 256, 0, stream>>>(h_f, h_b, Wout, bout, emis);
  k4_den  <<<256, 64, 0, stream>>>(words, emis, trans, st, et, denom);
  k4b_num <<<256, 64, 0, stream>>>(words, tags, emis, trans, st, et, num);
  k5_loss <<<1, 256, 0, stream>>>(num, denom, (float*)d_out);
}

// Round 3
// 600.249 us; speedup vs baseline: 1.2311x; 1.0411x over previous
//
#include <hip/hip_runtime.h>
#include <hip/hip_bf16.h>

// Sizes (fixed by the reference)
//  V=32000, T=48, E=128, HID=256, H=128, B=256, L=512, 4H=512
typedef unsigned short ushort_t;
typedef unsigned int uint_t;
typedef __bf16 bf16x8 __attribute__((ext_vector_type(8)));
typedef float f32x4 __attribute__((ext_vector_type(4)));
typedef float f32x16 __attribute__((ext_vector_type(16)));

#define L2E 1.44269504088896340736f
#define LN2 0.69314718055994530942f

// LDS-only barrier: does NOT drain vmcnt -> global loads/stores stay in flight.
#define WGBAR() __asm__ volatile("s_waitcnt lgkmcnt(0)\n\ts_barrier" ::: "memory")

static __device__ __forceinline__ float fexp2(float x) { return __builtin_amdgcn_exp2f(x); }
static __device__ __forceinline__ float flog2(float x) { return __builtin_amdgcn_logf(x); }
static __device__ __forceinline__ float frcp (float x) { return __builtin_amdgcn_rcpf(x); }

static __device__ __forceinline__ float sigm(float x) {
  return frcp(1.0f + fexp2(-L2E * x));
}
static __device__ __forceinline__ float tanha(float x) {
  return 1.0f - 2.0f * frcp(1.0f + fexp2(2.0f * L2E * x));
}

static __device__ __forceinline__ ushort_t f2bf(float f) {
  union { float f; uint_t u; } v; v.f = f;
  uint_t u = v.u;
  uint_t r = (u + 0x7fffu + ((u >> 16) & 1u)) >> 16;  // RNE
  return (ushort_t)r;
}
static __device__ __forceinline__ bf16x8 pack8(float4 a, float4 b) {
  uint4 u = make_uint4(
      (uint_t)f2bf(a.x) | ((uint_t)f2bf(a.y) << 16),
      (uint_t)f2bf(a.z) | ((uint_t)f2bf(a.w) << 16),
      (uint_t)f2bf(b.x) | ((uint_t)f2bf(b.y) << 16),
      (uint_t)f2bf(b.z) | ((uint_t)f2bf(b.w) << 16));
  return __builtin_bit_cast(bf16x8, u);
}
static __device__ __forceinline__ bf16x8 zero8() {
  uint4 z = make_uint4(0u, 0u, 0u, 0u);
  return __builtin_bit_cast(bf16x8, z);
}
static __device__ __forceinline__ uint2 pack4(float4 a) {
  return make_uint2((uint_t)f2bf(a.x) | ((uint_t)f2bf(a.y) << 16),
                    (uint_t)f2bf(a.z) | ((uint_t)f2bf(a.w) << 16));
}

// ---------------------------------------------------------------------------
// K2 v7 (unchanged from round 2 -- measured-good 366 us). Fully-fused BiLSTM.
// grid = 256 WGs x 512 thr; wg>>7 = dir, (wg&127)*2 = 2 batch rows.
//  - gate redistribution via in-register select (C rows alternate b0/b1:
//    every lane holds batch0 gates in reg[0], batch1 in reg[1]).
//  - xp production buffered across the 4 Q-phases, single 4x ds_write_b64.
// Raw lgkm-only barriers keep global loads/stores in flight across steps.
// ---------------------------------------------------------------------------
__global__ __launch_bounds__(512, 2) void k2_lstm(
    const int* __restrict__ words, const float* __restrict__ emb,
    const float* __restrict__ Wih_f, const float* __restrict__ Whh_f,
    const float* __restrict__ bih_f, const float* __restrict__ bhh_f,
    const float* __restrict__ Wih_b, const float* __restrict__ Whh_b,
    const float* __restrict__ bih_b, const float* __restrict__ bhh_b,
    ushort_t* __restrict__ h_f, ushort_t* __restrict__ h_b) {
  const int wg = blockIdx.x;
  const int dir = wg >> 7;
  const int r0 = (wg & 127) << 1;
  const float* Whh = dir ? Whh_b : Whh_f;
  const float* Wih = dir ? Wih_b : Wih_f;
  const float* bih = dir ? bih_b : bih_f;
  const float* bhh = dir ? bhh_b : bhh_f;
  ushort_t* hout = dir ? h_b : h_f;

  const int tid = threadIdx.x;
  const int w = tid >> 6;        // wave 0..7
  const int lane = tid & 63;
  const int l15 = lane & 15;
  const int kq = lane >> 4;      // 0..3

  __shared__ __align__(16) ushort_t hx[2][2][136];      //  1,088 B
  __shared__ __align__(16) ushort_t xp[2][16][128][4];  // 32,768 B
  __shared__ __align__(16) ushort_t xs[2][16][136];     //  8,704 B

  // ---- register-resident weight fragments (bf16), [quadrant][K-chunk] ----
  // B layout (16x16x32): col n = lane&15, k = (lane>>4)*8 + j
  bf16x8 wfh[4][4], wfx[4][4];
  float biasP[4];   // production bias for col w*16+l15, quadrant Q
#pragma unroll
  for (int Q = 0; Q < 4; ++Q) {
    const int n = Q * 128 + w * 16 + l15;
    biasP[Q] = bih[n] + bhh[n];
#pragma unroll
    for (int c = 0; c < 4; ++c) {
      const int k0 = c * 32 + kq * 8;
      const float* sh = Whh + n * 128 + k0;
      const float* sx = Wih + n * 128 + k0;
      wfh[Q][c] = pack8(*(const float4*)sh, *(const float4*)(sh + 4));
      wfx[Q][c] = pack8(*(const float4*)sx, *(const float4*)(sx + 4));
    }
  }

  const int ur = (lane >> 4) & 1;
  const int uj = w * 16 + l15;
  float cst = 0.f;

  // staging thread mapping: 512 thr cover 16 rows x 128 cols (4 floats each)
  const int sm = tid >> 5;          // xs row 0..15  (tl = sm>>1, r = sm&1)
  const int sc = (tid & 31) * 4;    // col 0..124
  const int str = r0 + (sm & 1);
  const int stl = sm >> 1;

  // production pack registers (live across the 4 Q sub-phases of a block)
  uint_t pd0[4], pd1[4];
  f32x4 pc = {0.f, 0.f, 0.f, 0.f};

  // ---- prologue ----
  if (tid < 256) hx[0][tid >> 7][tid & 127] = 0;   // h(-1) = 0
  {  // stage xs[1] = x(block 0)
    const int tg = stl;
    const int tf = dir ? (511 - tg) : tg;
    const int word = words[str * 512 + tf];
    float4 av = *(const float4*)(emb + (size_t)word * 128 + sc);
    *(uint2*)&xs[1][sm][sc] = pack4(av);
  }
  WGBAR();
  // produce xp[0] from xs[1] (16 dense MFMAs/wave), bias in C-init
#pragma unroll
  for (int Q = 0; Q < 4; ++Q) {
    f32x4 pc0 = {biasP[Q], biasP[Q], biasP[Q], biasP[Q]};
#pragma unroll
    for (int c = 0; c < 4; ++c) {
      bf16x8 af = __builtin_bit_cast(bf16x8, *(const uint4*)&xs[1][l15][kq * 8 + c * 32]);
      pc0 = __builtin_amdgcn_mfma_f32_16x16x32_bf16(af, wfx[Q][c], pc0, 0, 0, 0);
    }
#pragma unroll
    for (int rr = 0; rr < 4; ++rr) {
      const uint_t bb = (uint_t)f2bf(pc0[rr]);
      if (Q == 0) pd0[rr] = bb;
      else if (Q == 1) pd0[rr] |= bb << 16;
      else if (Q == 2) pd1[rr] = bb;
      else pd1[rr] |= bb << 16;
    }
  }
#pragma unroll
  for (int rr = 0; rr < 4; ++rr)
    *(uint2*)&xp[0][kq * 4 + rr][uj][0] = make_uint2(pd0[rr], pd1[rr]);
  {  // stage xs[0] = x(block 1)
    const int tg = 8 + stl;
    const int tf = dir ? (511 - tg) : tg;
    const int word = words[str * 512 + tf];
    float4 av = *(const float4*)(emb + (size_t)word * 128 + sc);
    *(uint2*)&xs[0][sm][sc] = pack4(av);
  }
  WGBAR();

  int sword = 0;
  float4 se0 = make_float4(0.f, 0.f, 0.f, 0.f);

#pragma unroll 1
  for (int i = 0; i < 64; ++i) {   // 64 blocks of 8 steps
    const int pcon = i & 1;        // consume xp[pcon]; production reads xs[pcon]
    const int ppro = pcon ^ 1;     // produce xp[ppro]; staging writes xs[ppro]
#pragma unroll
    for (int s = 0; s < 8; ++s) {
      const int t = i * 8 + s;
      const int p = t & 1;
      // xp consumption: one b64 read (Q0..Q3 packed for this lane's (ur,uj))
      const uint2 xq = *(const uint2*)&xp[pcon][2 * s + ur][uj][0];
      // staging pipeline for x(block i+2): word @s0, emb @s2, LDS write @s6
      if (i < 62) {
        if (s == 0) {
          const int tg = (i + 2) * 8 + stl;
          const int tf = dir ? (511 - tg) : tg;
          sword = words[str * 512 + tf];
        }
        if (s == 2) se0 = *(const float4*)(emb + (size_t)sword * 128 + sc);
        if (s == 6) *(uint2*)&xs[ppro][sm][sc] = pack4(se0);
      }
      // ---- recurrence MFMAs: gates_h = h @ Whh^T (K=128) ----
      f32x4 a0 = {0.f, 0.f, 0.f, 0.f}, a1 = a0, a2 = a0, a3 = a0;
      const ushort_t* abase = &hx[p][l15 & 1][kq * 8];
#pragma unroll
      for (int c = 0; c < 4; ++c) {
        bf16x8 af = __builtin_bit_cast(bf16x8, *(const uint4*)(abase + c * 32));
        a0 = __builtin_amdgcn_mfma_f32_16x16x32_bf16(af, wfh[0][c], a0, 0, 0, 0);
        a1 = __builtin_amdgcn_mfma_f32_16x16x32_bf16(af, wfh[1][c], a1, 0, 0, 0);
        a2 = __builtin_amdgcn_mfma_f32_16x16x32_bf16(af, wfh[2][c], a2, 0, 0, 0);
        a3 = __builtin_amdgcn_mfma_f32_16x16x32_bf16(af, wfh[3][c], a3, 0, 0, 0);
      }
      // ---- production MFMAs for block i+1 (independent; fills bubbles).
      //      Results buffered in pd0/pd1; single 4x b64 LDS write at s==7.
      if (i < 63) {
        const int Q = s >> 1;
        if ((s & 1) == 0) {
          pc = f32x4{biasP[Q], biasP[Q], biasP[Q], biasP[Q]};
          bf16x8 af0 = __builtin_bit_cast(bf16x8, *(const uint4*)&xs[pcon][l15][kq * 8]);
          bf16x8 af1 = __builtin_bit_cast(bf16x8, *(const uint4*)&xs[pcon][l15][kq * 8 + 32]);
          pc = __builtin_amdgcn_mfma_f32_16x16x32_bf16(af0, wfx[Q][0], pc, 0, 0, 0);
          pc = __builtin_amdgcn_mfma_f32_16x16x32_bf16(af1, wfx[Q][1], pc, 0, 0, 0);
        } else {
          bf16x8 af2 = __builtin_bit_cast(bf16x8, *(const uint4*)&xs[pcon][l15][kq * 8 + 64]);
          bf16x8 af3 = __builtin_bit_cast(bf16x8, *(const uint4*)&xs[pcon][l15][kq * 8 + 96]);
          pc = __builtin_amdgcn_mfma_f32_16x16x32_bf16(af2, wfx[Q][2], pc, 0, 0, 0);
          pc = __builtin_amdgcn_mfma_f32_16x16x32_bf16(af3, wfx[Q][3], pc, 0, 0, 0);
#pragma unroll
          for (int rr = 0; rr < 4; ++rr) {
            const uint_t bb = (uint_t)f2bf(pc[rr]);
            if (Q == 0) pd0[rr] = bb;
            else if (Q == 1) pd0[rr] |= bb << 16;
            else if (Q == 2) pd1[rr] = bb;
            else pd1[rr] |= bb << 16;
          }
          if (s == 7) {
#pragma unroll
            for (int rr = 0; rr < 4; ++rr)
              *(uint2*)&xp[ppro][kq * 4 + rr][uj][0] = make_uint2(pd0[rr], pd1[rr]);
          }
        }
      }
      // ---- gates: lane's own (ur,uj) pair -- reg[0]=batch0, reg[1]=batch1
      const float g0 = (ur ? a0[1] : a0[0]) + __builtin_bit_cast(float, xq.x << 16);
      const float g1 = (ur ? a1[1] : a1[0]) + __builtin_bit_cast(float, xq.x & 0xffff0000u);
      const float g2 = (ur ? a2[1] : a2[0]) + __builtin_bit_cast(float, xq.y << 16);
      const float g3 = (ur ? a3[1] : a3[0]) + __builtin_bit_cast(float, xq.y & 0xffff0000u);
      // activations (one chain per lane; lanes>=32 duplicate, stores guarded)
      const float si = sigm(g0), sf = sigm(g1), so = sigm(g3);
      const float tg = tanha(g2);
      cst = sf * cst + si * tg;
      const float h = so * tanha(cst);
      const ushort_t hb = f2bf(h);
      if (lane < 32) {
        hx[p ^ 1][ur][uj] = hb;
        const int tf = dir ? (511 - t) : t;
        hout[(tf * 256 + r0 + ur) * 128 + uj] = hb;  // stays in flight
      }
      WGBAR();
    }
  }
}

// ---------------------------------------------------------------------------
// K3: emis[t*256+b][48] = [h_f|h_b] @ Wout^T + bout  (fp32 out)
// Also zeroes the loss accumulator (block 0, thread 0) so K4 can atomicAdd.
// ---------------------------------------------------------------------------
__global__ __launch_bounds__(256, 2) void k3_emis(
    const ushort_t* __restrict__ h_f, const ushort_t* __restrict__ h_b,
    const float* __restrict__ Wout, const float* __restrict__ bout,
    float* __restrict__ emis, float* __restrict__ loss_out) {
  if (blockIdx.x == 0 && threadIdx.x == 0) loss_out[0] = 0.f;
  const int w = threadIdx.x >> 6;
  const int lane = threadIdx.x & 63;
  const int m31 = lane & 31;
  const int q = lane >> 5;
  const int Mbase = blockIdx.x * 128 + w * 32;

  bf16x8 bfr[2][16];
  float bo[2];
#pragma unroll
  for (int T = 0; T < 2; ++T) {
    const int n = T * 32 + m31;
    if (n < 48) {
      bo[T] = bout[n];
#pragma unroll
      for (int c = 0; c < 16; ++c) {
        const float* src = Wout + n * 256 + c * 16 + q * 8;
        bfr[T][c] = pack8(*(const float4*)src, *(const float4*)(src + 4));
      }
    } else {
      bo[T] = 0.f;
#pragma unroll
      for (int c = 0; c < 16; ++c) bfr[T][c] = zero8();
    }
  }
  f32x16 acc0{}, acc1{};
  const ushort_t* hrf = h_f + (long)(Mbase + m31) * 128;
  const ushort_t* hrb = h_b + (long)(Mbase + m31) * 128;
#pragma unroll
  for (int c = 0; c < 16; ++c) {
    const ushort_t* src = (c < 8) ? (hrf + c * 16 + q * 8) : (hrb + (c - 8) * 16 + q * 8);
    bf16x8 af = __builtin_bit_cast(bf16x8, *(const uint4*)src);
    acc0 = __builtin_amdgcn_mfma_f32_32x32x16_bf16(af, bfr[0][c], acc0, 0, 0, 0);
    acc1 = __builtin_amdgcn_mfma_f32_32x32x16_bf16(af, bfr[1][c], acc1, 0, 0, 0);
  }
#pragma unroll
  for (int T = 0; T < 2; ++T) {
    const int n = T * 32 + m31;
    if (n >= 48) continue;
    f32x16 A = T ? acc1 : acc0;
#pragma unroll
    for (int r = 0; r < 16; ++r) {
      const int row = (r & 3) + ((r >> 2) << 3) + (q << 2);
      emis[(long)(Mbase + row) * 48 + n] = A[r] + bo[T];
    }
  }
}

// ---------------------------------------------------------------------------
// K4 v6: fused CRF. wave 0 = forward algorithm (denominator), wave 1 = gold
// path score (numerator); per-block loss contribution atomicAdd'ed into out.
// Denominator chain changes vs round-2:
//  - NO explicit lgkmcnt(0) between ds_write and ds_reads: DS ops of one
//    wave complete in order, and C-level aliasing (ul[j] store vs ul[*]
//    loads) keeps program order. The compiler's own lgkm wait before the
//    FMA use transitively covers the write -> saves the exposed ~120cy
//    write-completion stall each of 512 serial steps.
//  - 8 accumulators (6-deep FMA chains instead of 12-deep).
//  - emis prefetch depth 4 (was 3) to cover L3 latency.
// 256 WGs x 128 thr.
// ---------------------------------------------------------------------------
__global__ void k4_crf(const int* __restrict__ words, const int* __restrict__ tags,
                       const float* __restrict__ emis, const float* __restrict__ trans,
                       const float* __restrict__ st, const float* __restrict__ et,
                       float* __restrict__ out) {
  const int b = blockIdx.x;
  const int tid = threadIdx.x;
  const int j = tid & 63;
  __shared__ float res[2];
  __shared__ __align__(16) float ul[64];

  if (tid >= 64) {
    // ---- wave 1: numerator (gold path score) ----
    float s = 0.f;
    int cnt = 0;
#pragma unroll 1
    for (int s8 = 0; s8 < 8; ++s8) {
      const int t = j + (s8 << 6);
      const int wv = words[b * 512 + t];
      const int tg = tags[b * 512 + t];
      const bool mt = (wv != 0);
      cnt += mt ? 1 : 0;
      if (t == 0) {
        s += st[tg] + emis[b * 48 + tg];
      } else if (mt) {
        const int tp = tags[b * 512 + t - 1];
        s += trans[tp * 48 + tg] + emis[(t * 256 + b) * 48 + tg];
      }
    }
#pragma unroll
    for (int d = 32; d; d >>= 1) {
      s += __shfl_xor(s, d, 64);
      cnt += __shfl_xor(cnt, d, 64);
    }
    if (j == 0) {
      const int lt = tags[b * 512 + cnt - 1];
      res[1] = s + et[lt];
    }
  } else {
    // ---- wave 0: denominator, forward algorithm in linear domain ----
    const bool v = j < 48;
    const int jj = v ? j : 47;
    float pcol[48];
#pragma unroll
    for (int i = 0; i < 48; ++i) pcol[i] = fexp2(trans[i * 48 + jj] * L2E);

    // mask bits: mb[q] bit s = (words[b*512 + q*64 + s] != 0)
    unsigned long long mb[8];
#pragma unroll
    for (int q = 0; q < 8; ++q)
      mb[q] = __ballot(words[b * 512 + q * 64 + j] != 0);

    float d = v ? fexp2((st[j] + emis[b * 48 + j]) * L2E) : 0.f;
    int S = 0, e_pend = 0;

    float em0 = v ? emis[(1 * 256 + b) * 48 + j] : 0.f;
    float em1 = v ? emis[(2 * 256 + b) * 48 + j] : 0.f;
    float em2 = v ? emis[(3 * 256 + b) * 48 + j] : 0.f;
    float em3 = v ? emis[(4 * 256 + b) * 48 + j] : 0.f;
    float Ecur = fexp2(em0 * L2E);

#pragma unroll 1
    for (int q = 0; q < 8; ++q) {
      const unsigned long long m = mb[q];
      const int s0 = (q == 0) ? 1 : 0;
#pragma unroll 1
      for (int s = s0; s < 64; ++s) {
        const int t = q * 64 + s;
        float E = Ecur;
        int eApp = 0;
        if ((s & 7) == 2) {   // fold lagged renorm into E (uniform branch)
          const float sc = __builtin_bit_cast(float, (uint_t)(127 - e_pend) << 23);
          E *= sc;
          eApp = e_pend;
        }
        const int tn = min(511, t + 4);
        em0 = em1; em1 = em2; em2 = em3;
        em3 = v ? emis[(tn * 256 + b) * 48 + j] : 0.f;  // vmcnt path, depth-4
        const float En = fexp2(em0 * L2E);              // E for t+1, off-chain

        // d-broadcast via LDS; DS ops of one wave complete in order, so no
        // explicit wait between the write and the reads is needed.
        ul[j] = d;
        float sA = 0.f, sB = 0.f, sC = 0.f, sD = 0.f;
        float sE = 0.f, sF = 0.f, sG = 0.f, sH = 0.f;
#pragma unroll
        for (int i8 = 0; i8 < 6; ++i8) {
          float4 u0 = *(const float4*)&ul[i8 * 8];
          float4 u1 = *(const float4*)&ul[i8 * 8 + 4];
          sA = fmaf(u0.x, pcol[i8 * 8 + 0], sA);
          sB = fmaf(u0.y, pcol[i8 * 8 + 1], sB);
          sC = fmaf(u0.z, pcol[i8 * 8 + 2], sC);
          sD = fmaf(u0.w, pcol[i8 * 8 + 3], sD);
          sE = fmaf(u1.x, pcol[i8 * 8 + 4], sE);
          sF = fmaf(u1.y, pcol[i8 * 8 + 5], sF);
          sG = fmaf(u1.z, pcol[i8 * 8 + 6], sG);
          sH = fmaf(u1.w, pcol[i8 * 8 + 7], sH);
        }
        const float nxt = (((sA + sB) + (sC + sD)) + ((sE + sF) + (sG + sH))) * E;
        if ((m >> s) & 1ull) {   // wave-uniform scalar branch, no memory
          d = v ? nxt : 0.f;
          S += eApp;
        }
        if ((s & 7) == 0) {      // lagged exponent measurement (any lane works)
          const int db = __builtin_amdgcn_readfirstlane(__builtin_bit_cast(int, d));
          e_pend = ((db >> 23) & 0xff) - 127;
        }
        Ecur = En;
      }
    }
    float uf = v ? d * fexp2(et[j] * L2E) : 0.f;
#pragma unroll
    for (int dd = 32; dd; dd >>= 1) uf += __shfl_xor(uf, dd, 64);
    if (j == 0) res[0] = ((float)S + flog2(uf)) * LN2;
  }
  __syncthreads();
  // loss = -mean(num - denom)  ->  accumulate (denom - num)/256
  if (tid == 0) atomicAdd(out, (res[0] - res[1]) * (1.0f / 256.0f));
}

// ---------------------------------------------------------------------------
extern "C" void kernel_launch(void* const* d_in, const int* in_sizes, int n_in,
                              void* d_out, int out_size, void* d_ws, size_t ws_size,
                              hipStream_t stream) {
  (void)in_sizes; (void)n_in; (void)out_size; (void)ws_size;
  const int*   words = (const int*)d_in[0];
  const int*   tags  = (const int*)d_in[1];
  // d_in[2] = mask (bool) -- unused; reconstructed as words != 0
  const float* emb   = (const float*)d_in[3];
  const float* Wih_f = (const float*)d_in[4];
  const float* Whh_f = (const float*)d_in[5];
  const float* bih_f = (const float*)d_in[6];
  const float* bhh_f = (const float*)d_in[7];
  const float* Wih_b = (const float*)d_in[8];
  const float* Whh_b = (const float*)d_in[9];
  const float* bih_b = (const float*)d_in[10];
  const float* bhh_b = (const float*)d_in[11];
  const float* Wout  = (const float*)d_in[12];
  const float* bout  = (const float*)d_in[13];
  const float* trans = (const float*)d_in[14];
  const float* st    = (const float*)d_in[15];
  const float* et    = (const float*)d_in[16];

  char* ws = (char*)d_ws;
  ushort_t* h_f   = (ushort_t*)(ws);                    // 33,554,432 B
  ushort_t* h_b   = (ushort_t*)(ws + 33554432);         // 33,554,432 B
  float*    emis  = (float*)   (ws + 67108864);         // 25,165,824 B
  // total ws needed: ~92.3 MB (within the known-good 125.8 MB envelope)

  k2_lstm <<<256, 512, 0, stream>>>(words, emb,
                                    Wih_f, Whh_f, bih_f, bhh_f,
                                    Wih_b, Whh_b, bih_b, bhh_b,
                                    h_f, h_b);
  k3_emis <<<1024, 256, 0, stream>>>(h_f, h_b, Wout, bout, emis, (float*)d_out);
  k4_crf  <<<256, 128, 0, stream>>>(words, tags, emis, trans, st, et, (float*)d_out);
}